// Round 1
// baseline (183.257 us; speedup 1.0000x reference)
//
#include <hip/hip_runtime.h>

typedef int v4i __attribute__((ext_vector_type(4)));

#define B_DIM   16
#define IN_DIM  8192
#define OUT_DIM 28672
#define KSTEPS  (IN_DIM / 64)   // 128 K-steps of K=64

// pack low bytes of 4 int32 lanes -> one dword (3x v_perm_b32)
static __device__ __forceinline__ unsigned pack_lo_bytes(v4i q) {
  unsigned t0 = __builtin_amdgcn_perm((unsigned)q.y, (unsigned)q.x, 0x00000400u); // {w0.b0, w1.b0, -, -}
  unsigned t1 = __builtin_amdgcn_perm((unsigned)q.w, (unsigned)q.z, 0x00000400u); // {w2.b0, w3.b0, -, -}
  return __builtin_amdgcn_perm(t1, t0, 0x05040100u);                              // {w0,w1,w2,w3}
}

// ---- pre-pass: per-row 2-level int8 quantization of x, packed in MFMA A-fragment order ----
// layout: byte for (b,k) at (k>>6)*1024 + ((k>>4)&3)*256 + b*16 + (k&15)
// so GEMM lane l at k-step kk reads 16B at kk*1024 + l*16  (l = g*16 + b)
__global__ __launch_bounds__(256) void xquant_kernel(
    const float* __restrict__ x,
    unsigned char* __restrict__ q1p,
    unsigned char* __restrict__ q2p,
    float* __restrict__ scales)
{
  const int b   = blockIdx.x;    // 16 blocks, one per batch row
  const int tid = threadIdx.x;   // 256 threads, 32 consecutive k each
  const float* xr = x + (size_t)b * IN_DIM + tid * 32;

  float v[32];
  float m = 0.0f;
#pragma unroll
  for (int i = 0; i < 8; ++i) {
    float4 f = ((const float4*)xr)[i];
    v[i*4+0] = f.x; v[i*4+1] = f.y; v[i*4+2] = f.z; v[i*4+3] = f.w;
    m = fmaxf(m, fmaxf(fmaxf(fabsf(f.x), fabsf(f.y)), fmaxf(fabsf(f.z), fabsf(f.w))));
  }
  // wave(64) max-reduce, then cross-wave via LDS
#pragma unroll
  for (int off = 32; off >= 1; off >>= 1)
    m = fmaxf(m, __shfl_xor(m, off));
  __shared__ float lmax[4];
  if ((tid & 63) == 0) lmax[tid >> 6] = m;
  __syncthreads();
  m = fmaxf(fmaxf(lmax[0], lmax[1]), fmaxf(lmax[2], lmax[3]));
  m = fmaxf(m, 1e-20f);

  const float s1   = m * (1.0f / 127.0f);
  const float inv1 = 1.0f / s1;
  const float s2   = s1 * (1.0f / 254.0f);
  const float inv2 = 1.0f / s2;
  if (tid == 0) { scales[b] = s1; scales[16 + b] = s2; }

#pragma unroll
  for (int h = 0; h < 2; ++h) {
    const int c = tid * 2 + h;              // 16-elem chunk index (k>>4)
    unsigned p1[4], p2[4];
#pragma unroll
    for (int d = 0; d < 4; ++d) {
      unsigned a1 = 0, a2 = 0;
#pragma unroll
      for (int j = 0; j < 4; ++j) {
        const float xv = v[h*16 + d*4 + j];
        float q1 = rintf(xv * inv1);
        q1 = fminf(127.0f, fmaxf(-127.0f, q1));
        const float r = fmaf(-s1, q1, xv);
        float q2 = rintf(r * inv2);
        q2 = fminf(127.0f, fmaxf(-127.0f, q2));
        a1 |= ((unsigned)((int)q1 & 0xff)) << (8*j);
        a2 |= ((unsigned)((int)q2 & 0xff)) << (8*j);
      }
      p1[d] = a1; p2[d] = a2;
    }
    const size_t off = (size_t)((c >> 2) * 1024 + (c & 3) * 256 + b * 16);
    *(v4i*)(q1p + off) = (v4i){(int)p1[0], (int)p1[1], (int)p1[2], (int)p1[3]};
    *(v4i*)(q2p + off) = (v4i){(int)p2[0], (int)p2[1], (int)p2[2], (int)p2[3]};
  }
}

// ---- main GEMM: 256 blocks x 7 waves; wave = 16 output channels over full K ----
__global__ __launch_bounds__(448) void qgemm_kernel(
    const int* __restrict__ w,              // int8 values stored as int32, [OUT_DIM][IN_DIM]
    const unsigned char* __restrict__ q1p,
    const unsigned char* __restrict__ q2p,
    const float* __restrict__ scales,       // s1[16], s2[16]
    const float* __restrict__ wscaler,      // [OUT_DIM]
    float* __restrict__ out)                // [16][OUT_DIM] f32
{
  const int lane = threadIdx.x & 63;
  const int wv   = threadIdx.x >> 6;        // 0..6
  const int col  = lane & 15;               // N (channel) within tile
  const int grp  = lane >> 4;               // k-group 0..3
  const int o    = blockIdx.x * 112 + wv * 16 + col;

  // B-fragment: lane reads w[o][kk*64 + grp*16 .. +15] = 16 int32 = 4x dwordx4
  const int* wp = w + (size_t)o * IN_DIM + grp * 16;
  const unsigned char* x1p = q1p + lane * 16;
  const unsigned char* x2p = q2p + lane * 16;

  v4i acc1 = {0,0,0,0}, acc2 = {0,0,0,0};

  // depth-2 software pipeline (128 % 2 == 0)
  v4i wb[2][4], xb1[2], xb2[2];
#pragma unroll
  for (int i = 0; i < 2; ++i) {
    const v4i* p = (const v4i*)(wp + i * 64);
    wb[i][0] = p[0]; wb[i][1] = p[1]; wb[i][2] = p[2]; wb[i][3] = p[3];
    xb1[i] = *(const v4i*)(x1p + (size_t)i * 1024);
    xb2[i] = *(const v4i*)(x2p + (size_t)i * 1024);
  }

  for (int kk = 0; kk < KSTEPS; kk += 2) {
#pragma unroll
    for (int i = 0; i < 2; ++i) {
      // issue prefetch for step kk+i+2 (clamped; tail reloads step 127 harmlessly)
      int kn = kk + i + 2; if (kn > KSTEPS - 1) kn = KSTEPS - 1;
      const v4i* p = (const v4i*)(wp + (size_t)kn * 64);
      v4i nw0 = p[0], nw1 = p[1], nw2 = p[2], nw3 = p[3];
      v4i nx1 = *(const v4i*)(x1p + (size_t)kn * 1024);
      v4i nx2 = *(const v4i*)(x2p + (size_t)kn * 1024);

      // pack current 16 int32 -> 16 int8 (low bytes), feed MFMA
      v4i bw;
      bw.x = (int)pack_lo_bytes(wb[i][0]);
      bw.y = (int)pack_lo_bytes(wb[i][1]);
      bw.z = (int)pack_lo_bytes(wb[i][2]);
      bw.w = (int)pack_lo_bytes(wb[i][3]);
      acc1 = __builtin_amdgcn_mfma_i32_16x16x64_i8(xb1[i], bw, acc1, 0, 0, 0);
      acc2 = __builtin_amdgcn_mfma_i32_16x16x64_i8(xb2[i], bw, acc2, 0, 0, 0);

      wb[i][0] = nw0; wb[i][1] = nw1; wb[i][2] = nw2; wb[i][3] = nw3;
      xb1[i] = nx1; xb2[i] = nx2;
    }
  }

  // epilogue: C/D layout col=lane&15, row=(lane>>4)*4+reg
  const float sc = wscaler[o];
#pragma unroll
  for (int r = 0; r < 4; ++r) {
    const int b = grp * 4 + r;
    const float val = scales[b] * (float)acc1[r] + scales[16 + b] * (float)acc2[r];
    out[(size_t)b * OUT_DIM + o] = val * sc;
  }
}

extern "C" void kernel_launch(void* const* d_in, const int* in_sizes, int n_in,
                              void* d_out, int out_size, void* d_ws, size_t ws_size,
                              hipStream_t stream) {
  const float* x       = (const float*)d_in[0];
  const int*   w       = (const int*)d_in[1];     // int8 range, int32 storage
  const float* wscaler = (const float*)d_in[2];
  float* out = (float*)d_out;

  unsigned char* ws  = (unsigned char*)d_ws;
  unsigned char* q1p = ws;                        // 128 KiB
  unsigned char* q2p = ws + 131072;               // 128 KiB
  float* scales      = (float*)(ws + 262144);     // 32 floats

  xquant_kernel<<<16, 256, 0, stream>>>(x, q1p, q2p, scales);
  qgemm_kernel<<<256, 448, 0, stream>>>(w, q1p, q2p, scales, wscaler, out);
}